// Round 1
// baseline (395.947 us; speedup 1.0000x reference)
//
#include <hip/hip_runtime.h>
#include <hip/hip_bf16.h>

#define E_EDGES 800000
#define NNODES  50000
#define HID     128

typedef __bf16 bf16x8 __attribute__((ext_vector_type(8)));
typedef float  f32x4  __attribute__((ext_vector_type(4)));
typedef unsigned short ushortx8 __attribute__((ext_vector_type(8)));

__device__ __forceinline__ unsigned short f2bf(float f) {
    union { float f; unsigned u; } v; v.f = f;
    unsigned r = v.u + 0x7FFFu + ((v.u >> 16) & 1u);
    return (unsigned short)(r >> 16);
}

__device__ __forceinline__ float silu(float x) {
    return x / (1.0f + __expf(-x));
}

// Pack W1[:, :256] and W2 into MFMA-B-fragment-contiguous bf16 layouts.
// W1p[((kc*8+nt)*64+lane)*8+j] = bf16(W1[nt*16+(lane&15)][kc*32+(lane>>4)*8+j]), kc 0..7
// W2p uses LDS feature permutation sigma(p) = (p&7)*16 + (p>>3), kc 0..3
// Wext[c] = {W1[c][256], W1[c][257], b1[c], b2[c]}
__global__ void pack_weights(const float* __restrict__ W1, const float* __restrict__ b1,
                             const float* __restrict__ W2, const float* __restrict__ b2,
                             unsigned short* __restrict__ W1p, unsigned short* __restrict__ W2p,
                             float4* __restrict__ Wext) {
    int i = blockIdx.x * 256 + threadIdx.x;
    if (i < 32768) {
        int j = i & 7, lane = (i >> 3) & 63, nt = (i >> 9) & 7, kc = i >> 12;
        int n = lane & 15, quad = lane >> 4;
        int k = kc * 32 + quad * 8 + j;       // 0..255
        int orow = nt * 16 + n;               // 0..127
        W1p[i] = f2bf(W1[orow * 258 + k]);
    } else if (i < 32768 + 16384) {
        int t = i - 32768;
        int j = t & 7, lane = (t >> 3) & 63, nt = (t >> 9) & 7, kc = t >> 12; // kc 0..3
        int n = lane & 15, quad = lane >> 4;
        int p = kc * 32 + quad * 8 + j;       // LDS position 0..127
        int f = (p & 7) * 16 + (p >> 3);      // permuted feature index
        W2p[t] = f2bf(W2[(nt * 16 + n) * 128 + f]);
    } else if (i < 32768 + 16384 + 128) {
        int c = i - (32768 + 16384);
        Wext[c] = make_float4(W1[c * 258 + 256], W1[c * 258 + 257], b1[c], b2[c]);
    }
}

__global__ void init_out(const float* __restrict__ coord, float* __restrict__ out, int n) {
    int i = blockIdx.x * 256 + threadIdx.x;
    if (i < n) out[i] = coord[i];
}

__launch_bounds__(256)
__global__ void edge_kernel(const float* __restrict__ h, const int* __restrict__ ei,
                            const float* __restrict__ cdiff, const float* __restrict__ eattr,
                            const ushortx8* __restrict__ W1p, const ushortx8* __restrict__ W2p,
                            const float4* __restrict__ Wext, const float* __restrict__ W3,
                            float* __restrict__ out) {
    __shared__ __align__(16) unsigned short x1[4][32][136]; // padded: 136*2B=272B stride -> 2-way banks
    __shared__ int   rowi[4][32];
    __shared__ int   coli[4][32];
    __shared__ float ea0[4][32];
    __shared__ float ea1[4][32];
    __shared__ float sbuf[4][32];

    const int w    = threadIdx.x >> 6;
    const int lane = threadIdx.x & 63;
    const int n    = lane & 15;
    const int quad = lane >> 4;
    const int ebase = (blockIdx.x * 4 + w) * 32;

    if (lane < 32) {
        int e = ebase + lane;
        rowi[w][lane] = ei[e];
        coli[w][lane] = ei[E_EDGES + e];
        const float2 ea = *(const float2*)(eattr + 2 * (long)e);
        ea0[w][lane] = ea.x;
        ea1[w][lane] = ea.y;
    }
    __syncthreads();

    // nodes for this lane's A rows (m = mt*16 + n)
    int nodeR[2] = { rowi[w][n], rowi[w][16 + n] };
    int nodeC[2] = { coli[w][n], coli[w][16 + n] };

    const f32x4 zero = { 0.f, 0.f, 0.f, 0.f };
    f32x4 acc[2][8];
#pragma unroll
    for (int mt = 0; mt < 2; ++mt)
#pragma unroll
        for (int nt = 0; nt < 8; ++nt) acc[mt][nt] = zero;

    // ---- layer 1: [32 edges, 256] @ W1[:, :256]^T ----
#pragma unroll
    for (int kc = 0; kc < 8; ++kc) {
        bf16x8 afrag[2];
#pragma unroll
        for (int mt = 0; mt < 2; ++mt) {
            int node = (kc < 4) ? nodeR[mt] : nodeC[mt];
            const float* p = h + (long)node * HID + (kc & 3) * 32 + quad * 8;
            float4 lo = *(const float4*)p;
            float4 hi = *(const float4*)(p + 4);
            ushortx8 u;
            u[0] = f2bf(lo.x); u[1] = f2bf(lo.y); u[2] = f2bf(lo.z); u[3] = f2bf(lo.w);
            u[4] = f2bf(hi.x); u[5] = f2bf(hi.y); u[6] = f2bf(hi.z); u[7] = f2bf(hi.w);
            afrag[mt] = __builtin_bit_cast(bf16x8, u);
        }
#pragma unroll
        for (int nt = 0; nt < 8; ++nt) {
            bf16x8 bfrag = __builtin_bit_cast(bf16x8, W1p[(kc * 8 + nt) * 64 + lane]);
            acc[0][nt] = __builtin_amdgcn_mfma_f32_16x16x32_bf16(afrag[0], bfrag, acc[0][nt], 0, 0, 0);
            acc[1][nt] = __builtin_amdgcn_mfma_f32_16x16x32_bf16(afrag[1], bfrag, acc[1][nt], 0, 0, 0);
        }
    }

    // epilogue 1: + b1 + edge_attr @ W1[:, 256:258], silu, write bf16 to LDS (permuted features)
    float4 wx[8];
#pragma unroll
    for (int nt = 0; nt < 8; ++nt) wx[nt] = Wext[nt * 16 + n];

#pragma unroll
    for (int mt = 0; mt < 2; ++mt) {
#pragma unroll
        for (int r = 0; r < 4; ++r) {
            int m = mt * 16 + quad * 4 + r;
            float a0 = ea0[w][m], a1 = ea1[w][m];
            ushortx8 u;
#pragma unroll
            for (int nt = 0; nt < 8; ++nt) {
                float v = acc[mt][nt][r] + wx[nt].z + a0 * wx[nt].x + a1 * wx[nt].y;
                u[nt] = f2bf(silu(v));
            }
            // position n*8+nt stores feature col nt*16+n
            *(ushortx8*)&x1[w][m][n * 8] = u;
        }
    }
    __syncthreads();

    // ---- layer 2: [32, 128] @ W2^T (permuted-k packing matches LDS layout) ----
#pragma unroll
    for (int mt = 0; mt < 2; ++mt)
#pragma unroll
        for (int nt = 0; nt < 8; ++nt) acc[mt][nt] = zero;

#pragma unroll
    for (int kc = 0; kc < 4; ++kc) {
        bf16x8 afrag[2];
#pragma unroll
        for (int mt = 0; mt < 2; ++mt)
            afrag[mt] = __builtin_bit_cast(bf16x8, *(const ushortx8*)&x1[w][mt * 16 + n][kc * 32 + quad * 8]);
#pragma unroll
        for (int nt = 0; nt < 8; ++nt) {
            bf16x8 bfrag = __builtin_bit_cast(bf16x8, W2p[(kc * 8 + nt) * 64 + lane]);
            acc[0][nt] = __builtin_amdgcn_mfma_f32_16x16x32_bf16(afrag[0], bfrag, acc[0][nt], 0, 0, 0);
            acc[1][nt] = __builtin_amdgcn_mfma_f32_16x16x32_bf16(afrag[1], bfrag, acc[1][nt], 0, 0, 0);
        }
    }

    // epilogue 2 + layer 3: silu(acc + b2) . W3, butterfly-reduce across n lanes
    float part[2][4] = { {0.f,0.f,0.f,0.f}, {0.f,0.f,0.f,0.f} };
#pragma unroll
    for (int nt = 0; nt < 8; ++nt) {
        float w3 = W3[nt * 16 + n];
        float bb2 = wx[nt].w;
#pragma unroll
        for (int mt = 0; mt < 2; ++mt)
#pragma unroll
            for (int r = 0; r < 4; ++r) {
                float v = silu(acc[mt][nt][r] + bb2);
                part[mt][r] += v * w3;
            }
    }
#pragma unroll
    for (int mask = 1; mask < 16; mask <<= 1) {
#pragma unroll
        for (int mt = 0; mt < 2; ++mt)
#pragma unroll
            for (int r = 0; r < 4; ++r)
                part[mt][r] += __shfl_xor(part[mt][r], mask, 64);
    }
    if (n == 0) {
#pragma unroll
        for (int mt = 0; mt < 2; ++mt)
#pragma unroll
            for (int r = 0; r < 4; ++r)
                sbuf[w][mt * 16 + quad * 4 + r] = part[mt][r];
    }
    __syncthreads();

    if (lane < 32) {
        int e = ebase + lane;
        float s = sbuf[w][lane];
        float t = tanhf(s) * 0.15f;  // *15 (COORDS_RANGE) / 100 (NORM_FACTOR)
        float c0 = cdiff[3 * (long)e + 0];
        float c1 = cdiff[3 * (long)e + 1];
        float c2 = cdiff[3 * (long)e + 2];
        int r = rowi[w][lane];
        atomicAdd(&out[r * 3 + 0], c0 * t);
        atomicAdd(&out[r * 3 + 1], c1 * t);
        atomicAdd(&out[r * 3 + 2], c2 * t);
    }
}

extern "C" void kernel_launch(void* const* d_in, const int* in_sizes, int n_in,
                              void* d_out, int out_size, void* d_ws, size_t ws_size,
                              hipStream_t stream) {
    const float* h     = (const float*)d_in[0];
    const float* coord = (const float*)d_in[1];
    const int*   ei    = (const int*)d_in[2];
    const float* cdiff = (const float*)d_in[3];
    const float* eattr = (const float*)d_in[4];
    const float* W1    = (const float*)d_in[5];
    const float* b1    = (const float*)d_in[6];
    const float* W2    = (const float*)d_in[7];
    const float* b2    = (const float*)d_in[8];
    const float* W3    = (const float*)d_in[9];
    float* out = (float*)d_out;

    unsigned short* W1p = (unsigned short*)d_ws;
    unsigned short* W2p = W1p + 32768;
    float4* Wext = (float4*)(W2p + 16384);

    pack_weights<<<(32768 + 16384 + 128 + 255) / 256, 256, 0, stream>>>(W1, b1, W2, b2, W1p, W2p, Wext);
    init_out<<<(3 * NNODES + 255) / 256, 256, 0, stream>>>(coord, out, 3 * NNODES);

    // 6250 blocks * 4 waves * 32 edges = 800000 exactly
    edge_kernel<<<E_EDGES / 128, 256, 0, stream>>>(h, ei, cdiff, eattr,
                                                   (const ushortx8*)W1p, (const ushortx8*)W2p,
                                                   (const float4*)Wext, W3, out);
}